// Round 1
// baseline (644.908 us; speedup 1.0000x reference)
//
#include <hip/hip_runtime.h>

#define N_NODES 100000
#define N_EDGES 50000
#define NNZ     3200000
#define D       32

// ---------------------------------------------------------------------------
// K1: X1 = X @ W1 + b1   (half-wave per node, W1 staged in LDS)
// ---------------------------------------------------------------------------
__global__ void k1_linear(const float* __restrict__ X,
                          const float* __restrict__ W1,
                          const float* __restrict__ b1,
                          float* __restrict__ X1) {
    __shared__ float Ws[D * D];
    __shared__ float bs[D];
    for (int i = threadIdx.x; i < D * D; i += blockDim.x) Ws[i] = W1[i];
    if (threadIdx.x < D) bs[threadIdx.x] = b1[threadIdx.x];
    __syncthreads();

    int half = threadIdx.x >> 5;              // 8 half-waves per 256-thread block
    int j    = threadIdx.x & 31;
    int node = blockIdx.x * (blockDim.x >> 5) + half;
    if (node >= N_NODES) return;

    float x   = X[node * D + j];
    float acc = bs[j];
#pragma unroll
    for (int k = 0; k < D; ++k) {
        float xk = __shfl(x, k, 32);
        acc = fmaf(xk, Ws[k * D + j], acc);
    }
    X1[node * D + j] = acc;
}

// ---------------------------------------------------------------------------
// K2: per-edge (one wave per edge).
//   segment of sorted `edges` found by binary search;
//   Xe = sum atts[i] * X1[vertex[i]]  (two incidences/iter via half-waves)
//   Ze = Xe @ W2b   (in-register GEMV, W2b = rows D..2D of W2)
//   scatter: Acc[v] += Ze  (atomic), deg[v] += 1
// ---------------------------------------------------------------------------
__global__ void k2_edge(const float* __restrict__ X1,
                        const float* __restrict__ atts,
                        const int* __restrict__ vertex,
                        const int* __restrict__ edges,
                        const float* __restrict__ W2,   // [2D, D] row-major
                        float* __restrict__ Acc,
                        int* __restrict__ deg) {
    __shared__ float Bs[D * D];
    for (int i = threadIdx.x; i < D * D; i += blockDim.x) Bs[i] = W2[D * D + i];
    __syncthreads();

    int wave = threadIdx.x >> 6;              // 4 waves per 256-thread block
    int lane = threadIdx.x & 63;
    int d    = lane & 31;
    int h    = lane >> 5;
    int e    = blockIdx.x * (blockDim.x >> 6) + wave;
    if (e >= N_EDGES) return;

    // lower_bound(edges, e) and lower_bound(edges, e+1)
    int lo = 0, hi = NNZ;
    while (lo < hi) { int mid = (lo + hi) >> 1; if (edges[mid] < e) lo = mid + 1; else hi = mid; }
    int start = lo;
    hi = NNZ;
    while (lo < hi) { int mid = (lo + hi) >> 1; if (edges[mid] < e + 1) lo = mid + 1; else hi = mid; }
    int end = lo;

    // accumulate Xe[e][d] across this edge's incidences (2 per iter)
    float acc = 0.f;
    for (int i = start + h; i < end; i += 2) {
        int   v = vertex[i];
        float a = atts[i];
        acc = fmaf(a, X1[v * D + d], acc);
    }
    // combine halves; xor-shuffle leaves the full sum in ALL 64 lanes
    acc += __shfl(acc, lane ^ 32, 64);

    // Ze[d] = sum_k Xe[k] * W2b[k][d]   (redundant in both halves)
    float ze = 0.f;
#pragma unroll
    for (int k = 0; k < D; ++k) {
        float xk = __shfl(acc, k, 32);
        ze = fmaf(xk, Bs[k * D + d], ze);
    }

    // scatter to nodes
    for (int i = start + h; i < end; i += 2) {
        int v = vertex[i];
        atomicAdd(&Acc[v * D + d], ze);
        if (d == 0) atomicAdd(&deg[v], 1);
    }
}

// ---------------------------------------------------------------------------
// K3: per-node epilogue.
//   s1  = X[v] @ W2a + b2
//   t   = 0.5*(deg[v]*s1 + Acc[v]) + 0.5*X0[v]
//   out = t @ W + b
// ---------------------------------------------------------------------------
__global__ void k3_node(const float* __restrict__ X,
                        const float* __restrict__ X0,
                        const float* __restrict__ Acc,
                        const int* __restrict__ deg,
                        const float* __restrict__ W2,   // [2D, D]; rows 0..D = W2a
                        const float* __restrict__ b2,
                        const float* __restrict__ Ww,
                        const float* __restrict__ bw,
                        float* __restrict__ out) {
    __shared__ float As[D * D];
    __shared__ float Ws[D * D];
    __shared__ float b2s[D];
    __shared__ float bws[D];
    for (int i = threadIdx.x; i < D * D; i += blockDim.x) {
        As[i] = W2[i];
        Ws[i] = Ww[i];
    }
    if (threadIdx.x < D) { b2s[threadIdx.x] = b2[threadIdx.x]; bws[threadIdx.x] = bw[threadIdx.x]; }
    __syncthreads();

    int half = threadIdx.x >> 5;
    int j    = threadIdx.x & 31;
    int node = blockIdx.x * (blockDim.x >> 5) + half;
    if (node >= N_NODES) return;

    float x  = X[node * D + j];
    float s1 = b2s[j];
#pragma unroll
    for (int k = 0; k < D; ++k) {
        float xk = __shfl(x, k, 32);
        s1 = fmaf(xk, As[k * D + j], s1);
    }
    float dg = (float)deg[node];
    float t  = 0.5f * (dg * s1 + Acc[node * D + j]) + 0.5f * X0[node * D + j];

    float o = bws[j];
#pragma unroll
    for (int k = 0; k < D; ++k) {
        float tk = __shfl(t, k, 32);
        o = fmaf(tk, Ws[k * D + j], o);
    }
    out[node * D + j] = o;
}

// ---------------------------------------------------------------------------
extern "C" void kernel_launch(void* const* d_in, const int* in_sizes, int n_in,
                              void* d_out, int out_size, void* d_ws, size_t ws_size,
                              hipStream_t stream) {
    const float* X      = (const float*)d_in[0];
    const float* X0     = (const float*)d_in[1];
    const float* atts   = (const float*)d_in[2];
    const float* W1w    = (const float*)d_in[3];
    const float* W1b    = (const float*)d_in[4];
    const float* W2w    = (const float*)d_in[5];
    const float* W2b    = (const float*)d_in[6];
    const float* Ww     = (const float*)d_in[7];
    const float* Wb     = (const float*)d_in[8];
    const int*   vertex = (const int*)d_in[9];
    const int*   edges  = (const int*)d_in[10];
    float*       out    = (float*)d_out;

    char* ws = (char*)d_ws;
    float* X1  = (float*)ws;                                        // N*D f32
    float* Acc = (float*)(ws + (size_t)N_NODES * D * 4);            // N*D f32
    int*   deg = (int*)  (ws + (size_t)2 * N_NODES * D * 4);        // N   i32

    // zero Acc + deg (contiguous)
    hipMemsetAsync(Acc, 0, (size_t)N_NODES * D * 4 + (size_t)N_NODES * 4, stream);

    k1_linear<<<(N_NODES + 7) / 8, 256, 0, stream>>>(X, W1w, W1b, X1);
    k2_edge  <<<(N_EDGES + 3) / 4, 256, 0, stream>>>(X1, atts, vertex, edges, W2w, Acc, deg);
    k3_node  <<<(N_NODES + 7) / 8, 256, 0, stream>>>(X, X0, Acc, deg, W2w, W2b, Ww, Wb, out);
}